// Round 2
// baseline (110742.896 us; speedup 1.0000x reference)
//
#include <hip/hip_runtime.h>
#include <cmath>

// B=1024, S=200, E=128, H=8, dh=16, T=199 steps
constexpr int Bn = 1024, Sn = 200, En = 128, Hn = 8, Tn = 199;
constexpr int SP = 204;   // padded LDS stride for encT rows (mult of 4 -> 16B align; 51i+q bank-group bijection)
constexpr long long LOGITS_N = (long long)Bn * Tn * Sn;
constexpr long long LOGP_OFF = LOGITS_N;
constexpr long long SOL_OFF  = LOGP_OFF + Bn;

#define NEG_INF (-__builtin_inff())

// ---------------------------------------------------------------------------
// Transpose Wk and Wp (64 KB each) so per-step matvecs are lane-coalesced.
// ---------------------------------------------------------------------------
__global__ __launch_bounds__(256) void transpose2_kernel(
    const float* __restrict__ Wk, const float* __restrict__ Wp,
    float* __restrict__ WkT, float* __restrict__ WpT)
{
  int idx = blockIdx.x * 256 + threadIdx.x;      // 32768 = 2 * 128*128
  int m = idx >> 14, r = idx & 16383;
  int i = r >> 7, e = r & 127;
  if (m == 0) WkT[e * En + i] = Wk[i * En + e];
  else        WpT[e * En + i] = Wp[i * En + e];
}

// ---------------------------------------------------------------------------
// Single persistent decode kernel: one block per batch element, enc in LDS.
// ---------------------------------------------------------------------------
__global__ __launch_bounds__(512) void decode_kernel(
    const float* __restrict__ enc, const float* __restrict__ vl, const float* __restrict__ vf,
    const float* __restrict__ Wq, const float* __restrict__ Wv, const float* __restrict__ Wo,
    const float* __restrict__ WkT, const float* __restrict__ WpT,
    float* __restrict__ out)
{
  const int b = blockIdx.x, tid = threadIdx.x;

  __shared__ float encT[En * SP];          // 104,448 B  (enc transposed: [e][s], stride 204)
  __shared__ float sc[Hn][Sn];             // scores -> attn
  __shared__ float wqh[Hn][132];           // per-head back-projected query (padded stride 132)
  __shared__ float eh[Hn * En];            // attn-weighted enc sums
  __shared__ float red_e[4][Hn * En];      // 16 KB partials for eh
  __shared__ float q[En], qf[En], hhq[En], lastv[En], firstv[En], ctx[En], octx[En], wp[En];
  __shared__ float uvals[Sn];
  __shared__ int   smask[Sn];
  __shared__ int   idx_s;
  __shared__ float logp_s;

  // ---- prologue: load enc transposed into LDS (coalesced global reads)
  for (int ix = tid; ix < Sn * En; ix += 512) {
    int s = ix >> 7, e = ix & 127;
    encT[e * SP + s] = enc[(size_t)b * Sn * En + ix];
  }
  if (tid < Sn) smask[tid] = (tid == 0) ? 1 : 0;   // depot masked from t=0
  if (tid < En) { lastv[tid] = vl[tid]; firstv[tid] = vf[tid]; }
  if (tid == 0) { logp_s = 0.f; out[SOL_OFF + (size_t)b * Sn] = 0.f; }
  __syncthreads();

  // ---- h_hat (mean over s), then hhq = h_hat @ Wq[0:128]
  if (tid < En) {
    const float* r = &encT[tid * SP];
    float s0 = 0, s1 = 0, s2 = 0, s3 = 0;
    for (int s = 0; s < Sn; s += 4) { s0 += r[s]; s1 += r[s+1]; s2 += r[s+2]; s3 += r[s+3]; }
    q[tid] = ((s0 + s1) + (s2 + s3)) * 0.005f;     // reuse q as h_hat temp
  }
  __syncthreads();
  if (tid < En) {
    float a0 = 0, a1 = 0, a2 = 0, a3 = 0;
    for (int i = 0; i < En; i += 4) {
      a0 += q[i    ] * Wq[(i    ) * En + tid];
      a1 += q[i + 1] * Wq[(i + 1) * En + tid];
      a2 += q[i + 2] * Wq[(i + 2) * En + tid];
      a3 += q[i + 3] * Wq[(i + 3) * En + tid];
    }
    hhq[tid] = (a0 + a1) + (a2 + a3);
  }
  __syncthreads();

  for (int t = 0; t < Tn; ++t) {
    // ---- qf = first @ Wq[256:384]  (only changes at t=0,1)
    if (t < 2) {
      if (tid < En) {
        float a0 = 0, a1 = 0, a2 = 0, a3 = 0;
        for (int i = 0; i < En; i += 4) {
          a0 += firstv[i    ] * Wq[(2 * En + i    ) * En + tid];
          a1 += firstv[i + 1] * Wq[(2 * En + i + 1) * En + tid];
          a2 += firstv[i + 2] * Wq[(2 * En + i + 2) * En + tid];
          a3 += firstv[i + 3] * Wq[(2 * En + i + 3) * En + tid];
        }
        qf[tid] = (a0 + a1) + (a2 + a3);
      }
      __syncthreads();
    }
    // ---- A: q = hhq + last @ Wq[128:256] + qf
    if (tid < En) {
      float a0 = 0, a1 = 0, a2 = 0, a3 = 0;
      for (int i = 0; i < En; i += 4) {
        a0 += lastv[i    ] * Wq[(En + i    ) * En + tid];
        a1 += lastv[i + 1] * Wq[(En + i + 1) * En + tid];
        a2 += lastv[i + 2] * Wq[(En + i + 2) * En + tid];
        a3 += lastv[i + 3] * Wq[(En + i + 3) * En + tid];
      }
      q[tid] = hhq[tid] + qf[tid] + (a0 + a1) + (a2 + a3);
    }
    __syncthreads();

    // ---- B: wq_h = Wk_h @ q_h, folded scale 1/sqrt(16)
    for (int o = tid; o < Hn * En; o += 512) {
      int h = o >> 7, i = o & 127;
      const float* wt = WkT + (h * 16) * En + i;
      const float* qp = &q[h * 16];
      float a = 0.f;
#pragma unroll
      for (int d = 0; d < 16; ++d) a += wt[d * En] * qp[d];
      wqh[h][i] = 0.25f * a;
    }
    __syncthreads();

    // ---- C: scores[h][s] = wq_h . enc_s  (400 threads: 50 s-quads x 8 heads)
    if (tid < 400) {
      int qd = tid >> 3, h = tid & 7, s0 = qd * 4;
      float a0 = 0, a1 = 0, a2 = 0, a3 = 0;
      for (int i = 0; i < En; ++i) {
        const float4 ev = *(const float4*)&encT[i * SP + s0];
        const float w = wqh[h][i];
        a0 += w * ev.x; a1 += w * ev.y; a2 += w * ev.z; a3 += w * ev.w;
      }
      sc[h][s0    ] = smask[s0    ] ? NEG_INF : a0;
      sc[h][s0 + 1] = smask[s0 + 1] ? NEG_INF : a1;
      sc[h][s0 + 2] = smask[s0 + 2] ? NEG_INF : a2;
      sc[h][s0 + 3] = smask[s0 + 3] ? NEG_INF : a3;
    }
    __syncthreads();

    // ---- D: softmax per head (wave w <-> head w)
    {
      int h = tid >> 6, lane = tid & 63;
      float m = NEG_INF;
      for (int s = lane; s < Sn; s += 64) m = fmaxf(m, sc[h][s]);
#pragma unroll
      for (int off = 32; off; off >>= 1) m = fmaxf(m, __shfl_xor(m, off));
      float sum = 0.f;
      for (int s = lane; s < Sn; s += 64) { float e_ = expf(sc[h][s] - m); sc[h][s] = e_; sum += e_; }
#pragma unroll
      for (int off = 32; off; off >>= 1) sum += __shfl_xor(sum, off);
      const float inv = 1.f / sum;
      for (int s = lane; s < Sn; s += 64) sc[h][s] *= inv;
    }
    __syncthreads();

    // ---- E1: e_h[i] partials = sum_s attn[h,s] * enc[s,i]  (thread = (i, s-part))
    {
      int i = tid & 127, part = tid >> 7;
      float ac[8] = {0, 0, 0, 0, 0, 0, 0, 0};
      for (int qd = part; qd < 50; qd += 4) {
        const float4 ev = *(const float4*)&encT[i * SP + qd * 4];
#pragma unroll
        for (int h = 0; h < 8; ++h) {
          const float4 at = *(const float4*)&sc[h][qd * 4];
          ac[h] += ev.x * at.x + ev.y * at.y + ev.z * at.z + ev.w * at.w;
        }
      }
#pragma unroll
      for (int h = 0; h < 8; ++h) red_e[part][h * En + i] = ac[h];
    }
    __syncthreads();
    // ---- E2: finalize eh
    for (int o = tid; o < Hn * En; o += 512)
      eh[o] = (red_e[0][o] + red_e[1][o]) + (red_e[2][o] + red_e[3][o]);
    __syncthreads();

    // ---- F: ctx[h*16+d] = sum_i eh[h][i] * Wv[i][h*16+d]
    if (tid < En) {
      const float* ep = &eh[(tid >> 4) * En];
      float a0 = 0, a1 = 0, a2 = 0, a3 = 0;
      for (int i = 0; i < En; i += 4) {
        a0 += ep[i    ] * Wv[(i    ) * En + tid];
        a1 += ep[i + 1] * Wv[(i + 1) * En + tid];
        a2 += ep[i + 2] * Wv[(i + 2) * En + tid];
        a3 += ep[i + 3] * Wv[(i + 3) * En + tid];
      }
      ctx[tid] = (a0 + a1) + (a2 + a3);
    }
    __syncthreads();

    // ---- G: octx = ctx @ Wo
    if (tid < En) {
      float a0 = 0, a1 = 0, a2 = 0, a3 = 0;
      for (int i = 0; i < En; i += 4) {
        a0 += ctx[i    ] * Wo[(i    ) * En + tid];
        a1 += ctx[i + 1] * Wo[(i + 1) * En + tid];
        a2 += ctx[i + 2] * Wo[(i + 2) * En + tid];
        a3 += ctx[i + 3] * Wo[(i + 3) * En + tid];
      }
      octx[tid] = (a0 + a1) + (a2 + a3);
    }
    __syncthreads();

    // ---- H: wp = Wp @ octx   (via WpT, coalesced)
    if (tid < En) {
      float a0 = 0, a1 = 0, a2 = 0, a3 = 0;
      for (int e = 0; e < En; e += 4) {
        a0 += octx[e    ] * WpT[(e    ) * En + tid];
        a1 += octx[e + 1] * WpT[(e + 1) * En + tid];
        a2 += octx[e + 2] * WpT[(e + 2) * En + tid];
        a3 += octx[e + 3] * WpT[(e + 3) * En + tid];
      }
      wp[tid] = (a0 + a1) + (a2 + a3);
    }
    __syncthreads();

    // ---- I: u[s] = tanh((wp . enc_s)/sqrt(128))*10  (2 threads per s)
    if (tid < 400) {
      int s = tid >> 1, half = tid & 1;
      const float* base = &encT[half * 64 * SP + s];
      const float* wpp = &wp[half * 64];
      float a0 = 0, a1 = 0;
      for (int i = 0; i < 64; i += 2) { a0 += wpp[i] * base[i * SP]; a1 += wpp[i + 1] * base[(i + 1) * SP]; }
      float a = a0 + a1;
      a += __shfl_xor(a, 1);
      if (half == 0) {
        const float uu = tanhf(a * 0.08838834764831845f) * 10.f;   // 1/sqrt(128)
        out[((size_t)b * Tn + t) * Sn + s] = uu;                   // raw logits
        uvals[s] = smask[s] ? NEG_INF : uu;
      }
    }
    __syncthreads();

    // ---- J: greedy argmax (first-index tie-break) + cross-entropy (wave 0)
    if (tid < 64) {
      float bv = NEG_INF; int bi = 1 << 30;
      for (int s = tid; s < Sn; s += 64) {
        const float v = uvals[s];
        if (v > bv || (v == bv && s < bi)) { bv = v; bi = s; }
      }
#pragma unroll
      for (int off = 32; off; off >>= 1) {
        const float ov = __shfl_xor(bv, off); const int oi = __shfl_xor(bi, off);
        if (ov > bv || (ov == bv && oi < bi)) { bv = ov; bi = oi; }
      }
      float sum = 0.f;
      for (int s = tid; s < Sn; s += 64) sum += expf(uvals[s] - bv);   // exp(-inf)=0
#pragma unroll
      for (int off = 32; off; off >>= 1) sum += __shfl_xor(sum, off);
      if (tid == 0) {
        idx_s = bi;
        logp_s += logf(sum);                       // ce = logsumexp - max (idx == argmax)
        out[SOL_OFF + (size_t)b * Sn + t + 1] = (float)bi;
      }
    }
    __syncthreads();

    // ---- K: state update
    {
      const int idx = idx_s;
      if (tid < En) {
        const float lv = encT[tid * SP + idx];
        lastv[tid] = lv;
        if (t == 0) firstv[tid] = lv;
      }
      if (tid == 0) smask[idx] = 1;
    }
    __syncthreads();
  }
  if (tid == 0) out[LOGP_OFF + b] = logp_s;
}

// ---------------------------------------------------------------------------
extern "C" void kernel_launch(void* const* d_in, const int* in_sizes, int n_in,
                              void* d_out, int out_size, void* d_ws, size_t ws_size,
                              hipStream_t stream)
{
  const float* enc = (const float*)d_in[0];
  // d_in[1] demands, d_in[2] capacities: unused by this forward
  const float* vl  = (const float*)d_in[3];
  const float* vf  = (const float*)d_in[4];
  const float* Wq  = (const float*)d_in[5];
  const float* Wk  = (const float*)d_in[6];
  const float* Wv  = (const float*)d_in[7];
  const float* Wo  = (const float*)d_in[8];
  const float* Wp  = (const float*)d_in[9];
  float* out = (float*)d_out;

  float* WkT = (float*)d_ws;
  float* WpT = WkT + En * En;

  hipLaunchKernelGGL(transpose2_kernel, dim3(128), dim3(256), 0, stream, Wk, Wp, WkT, WpT);
  hipLaunchKernelGGL(decode_kernel, dim3(Bn), dim3(512), 0, stream,
                     enc, vl, vf, Wq, Wv, Wo, WkT, WpT, out);
}

// Round 4
// 51787.250 us; speedup vs baseline: 2.1384x; 2.1384x over previous
//
#include <hip/hip_runtime.h>
#include <cmath>

// B=1024, S=200, E=128, H=8, dh=16, T=199 steps
constexpr int Bn = 1024, Sn = 200, En = 128, Hn = 8, Tn = 199;
constexpr long long LOGITS_N = (long long)Bn * Tn * Sn;
constexpr long long LOGP_OFF = LOGITS_N;
constexpr long long SOL_OFF  = LOGP_OFF + Bn;

#define NEG_INF (-__builtin_inff())

// ---------------------------------------------------------------------------
// qh[b] = (mean_s enc[b,s,:]) @ Wq[0:128,:]   (loop-invariant part of query)
// ---------------------------------------------------------------------------
__global__ __launch_bounds__(128) void hhat_qhat_kernel(
    const float* __restrict__ enc, const float* __restrict__ Wq, float* __restrict__ qh)
{
  const int b = blockIdx.x, e = threadIdx.x;
  const float* p = enc + (size_t)b * Sn * En + e;
  float s = 0.f;
  for (int i = 0; i < Sn; ++i) s += p[(size_t)i * En];
  __shared__ float hl[En];
  hl[e] = s * (1.0f / Sn);
  __syncthreads();
  float a = 0.f;
#pragma unroll 8
  for (int i = 0; i < En; ++i) a += hl[i] * Wq[i * En + e];
  qh[(size_t)b * En + e] = a;
}

// ---------------------------------------------------------------------------
// WkT[e][i] = Wk[i][e]  (so phase-B reads are lane-coalesced)
// ---------------------------------------------------------------------------
__global__ __launch_bounds__(256) void wkt_kernel(
    const float* __restrict__ Wk, float* __restrict__ WkT)
{
  int idx = blockIdx.x * 256 + threadIdx.x;   // 16384
  int i = idx >> 7, e = idx & 127;
  WkT[e * En + i] = Wk[i * En + e];
}

// ---------------------------------------------------------------------------
// Wop[i][j] = sum_k Wo[i][k] * Wp[j][k]   (= Wo @ Wp^T)
// Then phase G's wp[j] = sum_i ctx[i]*Wop[i][j] equals (Wp @ (ctx@Wo))[j],
// which is exactly what u_s = (ctx@Wo) . (enc_s@Wp) needs.
// ---------------------------------------------------------------------------
__global__ __launch_bounds__(256) void wop_kernel(
    const float* __restrict__ Wo, const float* __restrict__ Wp, float* __restrict__ Wop)
{
  int idx = blockIdx.x * 256 + threadIdx.x;   // 16384
  int i = idx >> 7, j = idx & 127;
  float a0 = 0.f, a1 = 0.f;
  for (int k = 0; k < En; k += 2) {
    a0 += Wo[i * En + k    ] * Wp[j * En + k    ];
    a1 += Wo[i * En + k + 1] * Wp[j * En + k + 1];
  }
  Wop[idx] = a0 + a1;
}

// ---------------------------------------------------------------------------
// Decode: one block (256 thr) per batch element; streams only enc[b] (100 KB,
// L2/L3-resident) + shared weights. Small LDS -> 4 blocks/CU for latency hiding.
// ---------------------------------------------------------------------------
__global__ __launch_bounds__(256, 4) void decode_kernel(
    const float* __restrict__ enc, const float* __restrict__ vl, const float* __restrict__ vf,
    const float* __restrict__ Wq, const float* __restrict__ Wv,
    const float* __restrict__ WkT, const float* __restrict__ Wop,
    const float* __restrict__ qh, float* __restrict__ out)
{
  const int b = blockIdx.x, tid = threadIdx.x;
  const float* encb = enc + (size_t)b * Sn * En;

  __shared__ float sc[Hn][Sn];          // scores -> attn (row = 800 B, 16B-aligned)
  __shared__ float wq[Hn * En];         // back-projected per-head query
  __shared__ float red[2][Hn * En];     // eh partials (2 s-halves)
  __shared__ float q[En], qf[En], hhq[En], lastv[En], firstv[En], ctx[En], wp[En];
  __shared__ float uvals[Sn];
  __shared__ int   smask[Sn];
  __shared__ int   idx_s;
  __shared__ float logp_s;

  if (tid < Sn) smask[tid] = (tid == 0) ? 1 : 0;   // depot masked from t=0
  if (tid < En) { lastv[tid] = vl[tid]; firstv[tid] = vf[tid]; hhq[tid] = qh[(size_t)b * En + tid]; }
  if (tid == 0) { logp_s = 0.f; out[SOL_OFF + (size_t)b * Sn] = 0.f; }
  __syncthreads();

  for (int t = 0; t < Tn; ++t) {
    // ---- qf = first @ Wq[256:384]  (changes only at t=0,1)
    if (t < 2) {
      if (tid < En) {
        float a0 = 0, a1 = 0, a2 = 0, a3 = 0;
        for (int i = 0; i < En; i += 4) {
          a0 += firstv[i    ] * Wq[(2 * En + i    ) * En + tid];
          a1 += firstv[i + 1] * Wq[(2 * En + i + 1) * En + tid];
          a2 += firstv[i + 2] * Wq[(2 * En + i + 2) * En + tid];
          a3 += firstv[i + 3] * Wq[(2 * En + i + 3) * En + tid];
        }
        qf[tid] = (a0 + a1) + (a2 + a3);
      }
      __syncthreads();
    }

    // ---- A: q = hhq + qf + last @ Wq[128:256]
    if (tid < En) {
      float a0 = 0, a1 = 0, a2 = 0, a3 = 0;
      for (int i = 0; i < En; i += 4) {
        a0 += lastv[i    ] * Wq[(En + i    ) * En + tid];
        a1 += lastv[i + 1] * Wq[(En + i + 1) * En + tid];
        a2 += lastv[i + 2] * Wq[(En + i + 2) * En + tid];
        a3 += lastv[i + 3] * Wq[(En + i + 3) * En + tid];
      }
      q[tid] = hhq[tid] + qf[tid] + (a0 + a1) + (a2 + a3);
    }
    __syncthreads();

    // ---- B: wq[h][e] = 0.25 * (Wk_h^T q_h)[e]   (1024 outputs, 4 per thread)
    for (int o = tid; o < Hn * En; o += 256) {
      const int h = o >> 7, i = o & 127;
      const float* wt = WkT + (h * 16) * En + i;
      const float* qp = &q[h * 16];
      float a = 0.f;
#pragma unroll
      for (int d = 0; d < 16; ++d) a += wt[d * En] * qp[d];
      wq[o] = 0.25f * a;
    }
    __syncthreads();

    // ---- C: scores[h][s] = wq_h . enc_s  (thread = s; per-lane dense row stream)
    if (tid < Sn) {
      const float4* er = (const float4*)(encb + (size_t)tid * En);
      float a[8] = {0, 0, 0, 0, 0, 0, 0, 0};
      for (int e4 = 0; e4 < En / 4; ++e4) {
        const float4 ev = er[e4];
#pragma unroll
        for (int h = 0; h < 8; ++h) {
          const float4 w4 = *(const float4*)&wq[h * En + e4 * 4];   // LDS broadcast
          a[h] += ev.x * w4.x + ev.y * w4.y + ev.z * w4.z + ev.w * w4.w;
        }
      }
      const bool mk = smask[tid] != 0;
#pragma unroll
      for (int h = 0; h < 8; ++h) sc[h][tid] = mk ? NEG_INF : a[h];
    }
    __syncthreads();

    // ---- D: softmax per head (wave w handles heads w, w+4)
    {
      const int wv_ = tid >> 6, lane = tid & 63;
      for (int h = wv_; h < Hn; h += 4) {
        float m = NEG_INF;
        for (int s = lane; s < Sn; s += 64) m = fmaxf(m, sc[h][s]);
#pragma unroll
        for (int off = 32; off; off >>= 1) m = fmaxf(m, __shfl_xor(m, off));
        float sum = 0.f;
        for (int s = lane; s < Sn; s += 64) { float e_ = expf(sc[h][s] - m); sc[h][s] = e_; sum += e_; }
#pragma unroll
        for (int off = 32; off; off >>= 1) sum += __shfl_xor(sum, off);
        const float inv = 1.f / sum;
        for (int s = lane; s < Sn; s += 64) sc[h][s] *= inv;
      }
    }
    __syncthreads();

    // ---- E: eh[h][i] = sum_s attn[h,s] enc[s,i]  (thread = (i, s-half); coalesced)
    {
      const int i = tid & 127, part = tid >> 7;
      const float* ep = encb + (size_t)(part * 100) * En + i;
      float ac[8] = {0, 0, 0, 0, 0, 0, 0, 0};
      for (int s4 = 0; s4 < 25; ++s4) {
        const int sb = part * 100 + s4 * 4;
        const float e0 = ep[(s4 * 4    ) * En];
        const float e1 = ep[(s4 * 4 + 1) * En];
        const float e2 = ep[(s4 * 4 + 2) * En];
        const float e3 = ep[(s4 * 4 + 3) * En];
#pragma unroll
        for (int h = 0; h < 8; ++h) {
          const float4 a4 = *(const float4*)&sc[h][sb];             // LDS broadcast b128
          ac[h] += e0 * a4.x + e1 * a4.y + e2 * a4.z + e3 * a4.w;
        }
      }
#pragma unroll
      for (int h = 0; h < 8; ++h) red[part][h * En + i] = ac[h];
    }
    __syncthreads();

    // ---- F: ctx[j] = sum_i eh[h(j)][i] * Wv[i][j]
    if (tid < En) {
      const int hb = (tid >> 4) * En;
      float a0 = 0, a1 = 0;
      for (int i = 0; i < En; i += 2) {
        const float e0 = red[0][hb + i    ] + red[1][hb + i    ];
        const float e1 = red[0][hb + i + 1] + red[1][hb + i + 1];
        a0 += e0 * Wv[(i    ) * En + tid];
        a1 += e1 * Wv[(i + 1) * En + tid];
      }
      ctx[tid] = a0 + a1;
    }
    __syncthreads();

    // ---- G: wp[j] = sum_i ctx[i] * Wop[i][j]   (Wop = Wo@Wp^T precomputed)
    if (tid < En) {
      float a0 = 0, a1 = 0, a2 = 0, a3 = 0;
      for (int i = 0; i < En; i += 4) {
        a0 += ctx[i    ] * Wop[(i    ) * En + tid];
        a1 += ctx[i + 1] * Wop[(i + 1) * En + tid];
        a2 += ctx[i + 2] * Wop[(i + 2) * En + tid];
        a3 += ctx[i + 3] * Wop[(i + 3) * En + tid];
      }
      wp[tid] = (a0 + a1) + (a2 + a3);
    }
    __syncthreads();

    // ---- I: u[s] = tanh((wp . enc_s)/sqrt(128))*10  (thread = s; dense row stream)
    if (tid < Sn) {
      const float4* er = (const float4*)(encb + (size_t)tid * En);
      float a0 = 0, a1 = 0, a2 = 0, a3 = 0;
      for (int e4 = 0; e4 < En / 4; ++e4) {
        const float4 ev = er[e4];
        const float4 w4 = *(const float4*)&wp[e4 * 4];              // LDS broadcast
        a0 += ev.x * w4.x; a1 += ev.y * w4.y; a2 += ev.z * w4.z; a3 += ev.w * w4.w;
      }
      const float a = (a0 + a1) + (a2 + a3);
      const float uu = tanhf(a * 0.08838834764831845f) * 10.f;      // 1/sqrt(128)
      out[((size_t)b * Tn + t) * Sn + tid] = uu;                    // raw logits
      uvals[tid] = smask[tid] ? NEG_INF : uu;
    }
    __syncthreads();

    // ---- J: greedy argmax (first-index tie-break) + cross-entropy (wave 0)
    if (tid < 64) {
      float bv = NEG_INF; int bi = 1 << 30;
      for (int s = tid; s < Sn; s += 64) {
        const float v = uvals[s];
        if (v > bv || (v == bv && s < bi)) { bv = v; bi = s; }
      }
#pragma unroll
      for (int off = 32; off; off >>= 1) {
        const float ov = __shfl_xor(bv, off); const int oi = __shfl_xor(bi, off);
        if (ov > bv || (ov == bv && oi < bi)) { bv = ov; bi = oi; }
      }
      float sum = 0.f;
      for (int s = tid; s < Sn; s += 64) sum += expf(uvals[s] - bv);   // exp(-inf)=0
#pragma unroll
      for (int off = 32; off; off >>= 1) sum += __shfl_xor(sum, off);
      if (tid == 0) {
        idx_s = bi;
        logp_s += logf(sum);                 // ce = logsumexp - max (idx == argmax)
        out[SOL_OFF + (size_t)b * Sn + t + 1] = (float)bi;
      }
    }
    __syncthreads();

    // ---- K: state update
    {
      const int idx = idx_s;
      if (tid < En) {
        const float lv = encb[(size_t)idx * En + tid];
        lastv[tid] = lv;
        if (t == 0) firstv[tid] = lv;
      }
      if (tid == 0) smask[idx] = 1;
    }
    __syncthreads();
  }
  if (tid == 0) out[LOGP_OFF + b] = logp_s;
}

// ---------------------------------------------------------------------------
extern "C" void kernel_launch(void* const* d_in, const int* in_sizes, int n_in,
                              void* d_out, int out_size, void* d_ws, size_t ws_size,
                              hipStream_t stream)
{
  const float* enc = (const float*)d_in[0];
  // d_in[1] demands, d_in[2] capacities: unused by this forward
  const float* vl  = (const float*)d_in[3];
  const float* vf  = (const float*)d_in[4];
  const float* Wq  = (const float*)d_in[5];
  const float* Wk  = (const float*)d_in[6];
  const float* Wv  = (const float*)d_in[7];
  const float* Wo  = (const float*)d_in[8];
  const float* Wp  = (const float*)d_in[9];
  float* out = (float*)d_out;

  float* WkT = (float*)d_ws;               // 16384 floats
  float* Wop = WkT + En * En;              // 16384 floats
  float* qh  = Wop + En * En;              // 1024*128 floats

  hipLaunchKernelGGL(wkt_kernel, dim3(64), dim3(256), 0, stream, Wk, WkT);
  hipLaunchKernelGGL(wop_kernel, dim3(64), dim3(256), 0, stream, Wo, Wp, Wop);
  hipLaunchKernelGGL(hhat_qhat_kernel, dim3(Bn), dim3(128), 0, stream, enc, Wq, qh);
  hipLaunchKernelGGL(decode_kernel, dim3(Bn), dim3(256), 0, stream,
                     enc, vl, vf, Wq, Wv, WkT, Wop, qh, out);
}